// Round 1
// baseline (4210.637 us; speedup 1.0000x reference)
//
#include <hip/hip_runtime.h>

#define NU_ 100000
#define NI_ 50000
#define E_  600000
#define DD  128

// ---------------------------------------------------------------------------
// Kernel 1: transpose W1, W2 (128x128) so GEMM reads rows of W^T coalesced.
// out[k][c] = W[c][k]
// ---------------------------------------------------------------------------
__global__ __launch_bounds__(256) void wtrans_kernel(
    const float* __restrict__ W1, const float* __restrict__ W2,
    float* __restrict__ W1T, float* __restrict__ W2T) {
  int t = blockIdx.x * 256 + threadIdx.x;  // 16384 total
  if (t >= DD * DD) return;
  int k = t >> 7, c = t & 127;
  W1T[k * DD + c] = W1[c * DD + k];
  W2T[k * DD + c] = W2[c * DD + k];
}

// ---------------------------------------------------------------------------
// Kernel 2: edge scatter. 32 lanes per edge, 4 dims (float4) per lane.
// Xu += feat_item[i]*norm_iu[e]        (scattered to row u)   [Xu pre-init = feat_user]
// Xi += feat_user[u]*norm_ui[e]        (scattered to row i)   [Xi pre-init = feat_item]
// em  = (feat_user[u]*norm_user[u]) * (feat_item[i]*norm_item[i])
// Mu += em (row u), Mi += em (row i)   [pre-init = 0]
// ---------------------------------------------------------------------------
__global__ __launch_bounds__(256) void edge_scatter_kernel(
    const float* __restrict__ fu, const float* __restrict__ fi,
    const float* __restrict__ nu, const float* __restrict__ ni,
    const float* __restrict__ nui, const float* __restrict__ niu,
    const int* __restrict__ eu, const int* __restrict__ ei,
    float* __restrict__ Xu, float* __restrict__ Mu,
    float* __restrict__ Xi, float* __restrict__ Mi) {
  int gid = blockIdx.x * 256 + threadIdx.x;
  int e = gid >> 5;
  if (e >= E_) return;
  int lane = gid & 31;
  int u = eu[e];
  int it = ei[e];
  float w_iu = niu[e];
  float w_ui = nui[e];
  float su = nu[u];
  float si = ni[it];

  const float4 fuv = *reinterpret_cast<const float4*>(fu + (size_t)u * DD + lane * 4);
  const float4 fiv = *reinterpret_cast<const float4*>(fi + (size_t)it * DD + lane * 4);

  float4 em;
  em.x = (fuv.x * su) * (fiv.x * si);
  em.y = (fuv.y * su) * (fiv.y * si);
  em.z = (fuv.z * su) * (fiv.z * si);
  em.w = (fuv.w * su) * (fiv.w * si);

  float* au = Xu + (size_t)u * DD + lane * 4;
  float* mu = Mu + (size_t)u * DD + lane * 4;
  float* ai = Xi + (size_t)it * DD + lane * 4;
  float* mi = Mi + (size_t)it * DD + lane * 4;

  atomicAdd(au + 0, fiv.x * w_iu);
  atomicAdd(au + 1, fiv.y * w_iu);
  atomicAdd(au + 2, fiv.z * w_iu);
  atomicAdd(au + 3, fiv.w * w_iu);

  atomicAdd(ai + 0, fuv.x * w_ui);
  atomicAdd(ai + 1, fuv.y * w_ui);
  atomicAdd(ai + 2, fuv.z * w_ui);
  atomicAdd(ai + 3, fuv.w * w_ui);

  atomicAdd(mu + 0, em.x);
  atomicAdd(mu + 1, em.y);
  atomicAdd(mu + 2, em.z);
  atomicAdd(mu + 3, em.w);

  atomicAdd(mi + 0, em.x);
  atomicAdd(mi + 1, em.y);
  atomicAdd(mi + 2, em.z);
  atomicAdd(mi + 3, em.w);
}

// ---------------------------------------------------------------------------
// Kernel 3: fused h = X@W1^T + M@W2^T + (b1+b2) -> leakyrelu -> L2 normalize.
// Block: 256 threads, 32 output rows x 128 cols. Thread (tr=tid>>5, tc=tid&31)
// owns rows tr*4..tr*4+3, cols tc*4..tc*4+3 (4x4 acc).
// X,M tiles staged TRANSPOSED in LDS (k-major) so inner-loop reads broadcast.
// ---------------------------------------------------------------------------
__global__ __launch_bounds__(256) void gemm_post_kernel(
    const float* __restrict__ Xu, const float* __restrict__ Mu,
    const float* __restrict__ Xi, const float* __restrict__ Mi,
    const float* __restrict__ W1T, const float* __restrict__ W2T,
    const float* __restrict__ b1, const float* __restrict__ b2,
    float* __restrict__ out, int nblk_u) {
  __shared__ float XT[DD][36];  // padded: 36*4B=144B row stride (16B aligned, bank-rotating)
  __shared__ float MT[DD][36];

  int blk = blockIdx.x;
  const float* X;
  const float* M;
  float* o;
  int nrows, row0;
  if (blk < nblk_u) {
    X = Xu; M = Mu; o = out; nrows = NU_; row0 = blk * 32;
  } else {
    X = Xi; M = Mi; o = out + (size_t)NU_ * DD; nrows = NI_; row0 = (blk - nblk_u) * 32;
  }

  int tid = threadIdx.x;

  // ---- stage 32 rows of X and M, transposed, into LDS ----
  {
    int srow = tid >> 3;  // 0..31
    int kq = tid & 7;     // 0..7
    bool rvalid = (row0 + srow) < nrows;
    const float* xr = X + (size_t)(row0 + srow) * DD;
    const float* mr = M + (size_t)(row0 + srow) * DD;
#pragma unroll
    for (int j = 0; j < 4; j++) {
      int kv = (kq + j * 8) * 4;  // float index within row
      float4 xv = make_float4(0.f, 0.f, 0.f, 0.f);
      float4 mv = make_float4(0.f, 0.f, 0.f, 0.f);
      if (rvalid) {
        xv = *reinterpret_cast<const float4*>(xr + kv);
        mv = *reinterpret_cast<const float4*>(mr + kv);
      }
      XT[kv + 0][srow] = xv.x; XT[kv + 1][srow] = xv.y;
      XT[kv + 2][srow] = xv.z; XT[kv + 3][srow] = xv.w;
      MT[kv + 0][srow] = mv.x; MT[kv + 1][srow] = mv.y;
      MT[kv + 2][srow] = mv.z; MT[kv + 3][srow] = mv.w;
    }
  }
  __syncthreads();

  int tc = tid & 31;   // col group: cols tc*4..tc*4+3
  int tr = tid >> 5;   // row group: rows tr*4..tr*4+3

  float acc[4][4] = {{0.f}};

#pragma unroll 4
  for (int k = 0; k < DD; k++) {
    float4 wv = *reinterpret_cast<const float4*>(W1T + k * DD + tc * 4);
    float4 xv = *reinterpret_cast<const float4*>(&XT[k][tr * 4]);
    float x[4] = {xv.x, xv.y, xv.z, xv.w};
    float w[4] = {wv.x, wv.y, wv.z, wv.w};
#pragma unroll
    for (int ri = 0; ri < 4; ri++)
#pragma unroll
      for (int cj = 0; cj < 4; cj++) acc[ri][cj] += x[ri] * w[cj];
  }
#pragma unroll 4
  for (int k = 0; k < DD; k++) {
    float4 wv = *reinterpret_cast<const float4*>(W2T + k * DD + tc * 4);
    float4 xv = *reinterpret_cast<const float4*>(&MT[k][tr * 4]);
    float x[4] = {xv.x, xv.y, xv.z, xv.w};
    float w[4] = {wv.x, wv.y, wv.z, wv.w};
#pragma unroll
    for (int ri = 0; ri < 4; ri++)
#pragma unroll
      for (int cj = 0; cj < 4; cj++) acc[ri][cj] += x[ri] * w[cj];
  }

  // ---- epilogue: bias, leaky relu, row L2 norm, store ----
  float4 b1v = *reinterpret_cast<const float4*>(b1 + tc * 4);
  float4 b2v = *reinterpret_cast<const float4*>(b2 + tc * 4);
  float bias[4] = {b1v.x + b2v.x, b1v.y + b2v.y, b1v.z + b2v.z, b1v.w + b2v.w};

#pragma unroll
  for (int ri = 0; ri < 4; ri++) {
    float v[4];
    float ss = 0.f;
#pragma unroll
    for (int cj = 0; cj < 4; cj++) {
      float h = acc[ri][cj] + bias[cj];
      h = (h > 0.f) ? h : 0.2f * h;
      v[cj] = h;
      ss += h * h;
    }
    // reduce across the 32 lanes (tc) of this row group; lanes with the same
    // tr are contiguous 32-lane halves of a wave, so xor masks 1..16 stay inside.
#pragma unroll
    for (int m = 1; m < 32; m <<= 1) ss += __shfl_xor(ss, m);
    float inv = 1.0f / fmaxf(sqrtf(ss), 1e-12f);
    int row = row0 + tr * 4 + ri;
    if (row < nrows) {
      float4 ov = make_float4(v[0] * inv, v[1] * inv, v[2] * inv, v[3] * inv);
      *reinterpret_cast<float4*>(o + (size_t)row * DD + tc * 4) = ov;
    }
  }
}

// ---------------------------------------------------------------------------
extern "C" void kernel_launch(void* const* d_in, const int* in_sizes, int n_in,
                              void* d_out, int out_size, void* d_ws, size_t ws_size,
                              hipStream_t stream) {
  const float* fu  = (const float*)d_in[0];   // feat_user  [NU,128]
  const float* fi  = (const float*)d_in[1];   // feat_item  [NI,128]
  const float* nu  = (const float*)d_in[2];   // norm_user  [NU,1]
  const float* ni  = (const float*)d_in[3];   // norm_item  [NI,1]
  const float* nui = (const float*)d_in[4];   // norm_ui    [E,1]
  const float* niu = (const float*)d_in[5];   // norm_iu    [E,1]
  const float* W1  = (const float*)d_in[6];   // [128,128]
  const float* b1  = (const float*)d_in[7];   // [128]
  const float* W2  = (const float*)d_in[8];   // [128,128]
  const float* b2  = (const float*)d_in[9];   // [128]
  const int* eu    = (const int*)d_in[10];    // [E]
  const int* ei    = (const int*)d_in[11];    // [E]
  float* out = (float*)d_out;
  float* ws = (float*)d_ws;

  size_t off = 0;
  float* Xu = ws + off; off += (size_t)NU_ * DD;   // feat_user + agg_user
  float* Mu = ws + off; off += (size_t)NU_ * DD;   // msg_user
  float* Xi = ws + off; off += (size_t)NI_ * DD;   // feat_item + agg_item
  float* Mi = ws + off; off += (size_t)NI_ * DD;   // msg_item
  float* W1T = ws + off; off += (size_t)DD * DD;
  float* W2T = ws + off; off += (size_t)DD * DD;

  // init accumulators: X = feat (folds the "+feat" add), M = 0
  hipMemcpyAsync(Xu, fu, (size_t)NU_ * DD * sizeof(float), hipMemcpyDeviceToDevice, stream);
  hipMemcpyAsync(Xi, fi, (size_t)NI_ * DD * sizeof(float), hipMemcpyDeviceToDevice, stream);
  hipMemsetAsync(Mu, 0, (size_t)NU_ * DD * sizeof(float), stream);
  hipMemsetAsync(Mi, 0, (size_t)NI_ * DD * sizeof(float), stream);

  wtrans_kernel<<<(DD * DD + 255) / 256, 256, 0, stream>>>(W1, W2, W1T, W2T);

  int nthreads_edge = E_ * 32;
  edge_scatter_kernel<<<(nthreads_edge + 255) / 256, 256, 0, stream>>>(
      fu, fi, nu, ni, nui, niu, eu, ei, Xu, Mu, Xi, Mi);

  int nblk_u = (NU_ + 31) / 32;  // 3125
  int nblk_i = (NI_ + 31) / 32;  // 1563
  gemm_post_kernel<<<nblk_u + nblk_i, 256, 0, stream>>>(
      Xu, Mu, Xi, Mi, W1T, W2T, b1, b2, out, nblk_u);
}

// Round 2
// 467.025 us; speedup vs baseline: 9.0159x; 9.0159x over previous
//
#include <hip/hip_runtime.h>

#define NU_ 100000
#define NI_ 50000
#define E_  600000
#define DD  128
#define NT_ (NU_ + NI_)
#define SCAN_BLK 2048
#define NSCAN ((NT_ + SCAN_BLK - 1) / SCAN_BLK)   // 74

// ---------------------------------------------------------------------------
// Kernel: transpose W1, W2 (128x128) so GEMM reads rows of W^T coalesced.
// ---------------------------------------------------------------------------
__global__ __launch_bounds__(256) void wtrans_kernel(
    const float* __restrict__ W1, const float* __restrict__ W2,
    float* __restrict__ W1T, float* __restrict__ W2T) {
  int t = blockIdx.x * 256 + threadIdx.x;
  if (t >= DD * DD) return;
  int k = t >> 7, c = t & 127;
  W1T[k * DD + c] = W1[c * DD + k];
  W2T[k * DD + c] = W2[c * DD + k];
}

// ---------------------------------------------------------------------------
// CSR build: degree count -> exclusive scan -> fill adjacency.
// Combined node space: [0,NU) users, [NU,NT) items. 2E adjacency entries.
// ---------------------------------------------------------------------------
__global__ __launch_bounds__(256) void count_deg_kernel(
    const int* __restrict__ eu, const int* __restrict__ ei, int* __restrict__ deg) {
  int e = blockIdx.x * 256 + threadIdx.x;
  if (e >= E_) return;
  atomicAdd(&deg[eu[e]], 1);
  atomicAdd(&deg[NU_ + ei[e]], 1);
}

__global__ __launch_bounds__(256) void scan1_kernel(
    const int* __restrict__ deg, int* __restrict__ off, int* __restrict__ bsum) {
  __shared__ int ts[256];
  int tid = threadIdx.x;
  int base = blockIdx.x * SCAN_BLK + tid * 8;
  int v[8];
  int s = 0;
#pragma unroll
  for (int j = 0; j < 8; j++) {
    v[j] = s;
    int idx = base + j;
    s += (idx < NT_) ? deg[idx] : 0;
  }
  ts[tid] = s;
  __syncthreads();
  for (int ofs = 1; ofs < 256; ofs <<= 1) {
    int add = (tid >= ofs) ? ts[tid - ofs] : 0;
    __syncthreads();
    ts[tid] += add;
    __syncthreads();
  }
  int texcl = ts[tid] - s;  // exclusive prefix of this thread's 8-chunk
#pragma unroll
  for (int j = 0; j < 8; j++) {
    int idx = base + j;
    if (idx < NT_) off[idx] = texcl + v[j];
  }
  if (tid == 255) bsum[blockIdx.x] = ts[255];
}

__global__ void scan2_kernel(int* __restrict__ bsum) {
  if (threadIdx.x == 0) {
    int s = 0;
    for (int n = 0; n < NSCAN; n++) {
      int t = bsum[n];
      bsum[n] = s;
      s += t;
    }
  }
}

__global__ __launch_bounds__(256) void scan3_kernel(
    int* __restrict__ off, int* __restrict__ cur, const int* __restrict__ bsum) {
  int i = blockIdx.x * 256 + threadIdx.x;
  if (i >= NT_) return;
  int v = off[i] + bsum[i >> 11];  // SCAN_BLK = 2048
  off[i] = v;
  cur[i] = v;
}

// adjacency entry: (neighbor index, edge weight). Node-side scale read at
// gather time from the (fully cached) norm tables.
__global__ __launch_bounds__(256) void fill_adj_kernel(
    const int* __restrict__ eu, const int* __restrict__ ei,
    const float* __restrict__ nui, const float* __restrict__ niu,
    int* __restrict__ cur, int2* __restrict__ adj) {
  int e = blockIdx.x * 256 + threadIdx.x;
  if (e >= E_) return;
  int u = eu[e], i = ei[e];
  int pu = atomicAdd(&cur[u], 1);
  adj[pu] = make_int2(i, __float_as_int(niu[e]));
  int pi = atomicAdd(&cur[NU_ + i], 1);
  adj[pi] = make_int2(u, __float_as_int(nui[e]));
}

// ---------------------------------------------------------------------------
// Gather: 32 lanes per node (float4/lane), 8 nodes per 256-block.
//   X[g] = feat[g] + sum_n feat_nb[idx_n] * w_n
//   M[g] = (feat[g]*s_own) .* sum_n feat_nb[idx_n] * s_nb[idx_n]
// Every row written exactly once -> no atomics.
// ---------------------------------------------------------------------------
__global__ __launch_bounds__(256) void gather_kernel(
    const float* __restrict__ fu, const float* __restrict__ fi,
    const float* __restrict__ nu, const float* __restrict__ ni,
    const int* __restrict__ off, const int* __restrict__ deg,
    const int2* __restrict__ adj,
    float* __restrict__ Xu, float* __restrict__ Mu,
    float* __restrict__ Xi, float* __restrict__ Mi) {
  int g = blockIdx.x * 8 + (threadIdx.x >> 5);
  if (g >= NT_) return;
  int lane = threadIdx.x & 31;
  bool isU = g < NU_;
  const float* nbF = isU ? fi : fu;
  const float* nbS = isU ? ni : nu;
  int start = off[g];
  int cnt = deg[g];

  float4 accA = make_float4(0.f, 0.f, 0.f, 0.f);
  float4 accM = make_float4(0.f, 0.f, 0.f, 0.f);
  for (int n = start; n < start + cnt; n++) {
    int2 a = adj[n];                 // broadcast across the 32 lanes
    int idx = a.x;
    float w = __int_as_float(a.y);
    float snb = nbS[idx];
    const float4 f = *reinterpret_cast<const float4*>(nbF + (size_t)idx * DD + lane * 4);
    accA.x += f.x * w;  accA.y += f.y * w;  accA.z += f.z * w;  accA.w += f.w * w;
    accM.x += f.x * snb; accM.y += f.y * snb; accM.z += f.z * snb; accM.w += f.w * snb;
  }

  int lrow = isU ? g : g - NU_;
  const float* own = (isU ? fu : fi) + (size_t)lrow * DD;
  float sown = isU ? nu[lrow] : ni[lrow];
  float* X = (isU ? Xu : Xi) + (size_t)lrow * DD;
  float* M = (isU ? Mu : Mi) + (size_t)lrow * DD;

  float4 fo = *reinterpret_cast<const float4*>(own + lane * 4);
  float4 xv = make_float4(fo.x + accA.x, fo.y + accA.y, fo.z + accA.z, fo.w + accA.w);
  float4 mv = make_float4(fo.x * sown * accM.x, fo.y * sown * accM.y,
                          fo.z * sown * accM.z, fo.w * sown * accM.w);
  *reinterpret_cast<float4*>(X + lane * 4) = xv;
  *reinterpret_cast<float4*>(M + lane * 4) = mv;
}

// ---------------------------------------------------------------------------
// Fused h = X@W1^T + M@W2^T + (b1+b2) -> leakyrelu -> L2 normalize.
// ---------------------------------------------------------------------------
__global__ __launch_bounds__(256) void gemm_post_kernel(
    const float* __restrict__ Xu, const float* __restrict__ Mu,
    const float* __restrict__ Xi, const float* __restrict__ Mi,
    const float* __restrict__ W1T, const float* __restrict__ W2T,
    const float* __restrict__ b1, const float* __restrict__ b2,
    float* __restrict__ out, int nblk_u) {
  __shared__ float XT[DD][36];
  __shared__ float MT[DD][36];

  int blk = blockIdx.x;
  const float* X;
  const float* M;
  float* o;
  int nrows, row0;
  if (blk < nblk_u) {
    X = Xu; M = Mu; o = out; nrows = NU_; row0 = blk * 32;
  } else {
    X = Xi; M = Mi; o = out + (size_t)NU_ * DD; nrows = NI_; row0 = (blk - nblk_u) * 32;
  }

  int tid = threadIdx.x;

  {
    int srow = tid >> 3;
    int kq = tid & 7;
    bool rvalid = (row0 + srow) < nrows;
    const float* xr = X + (size_t)(row0 + srow) * DD;
    const float* mr = M + (size_t)(row0 + srow) * DD;
#pragma unroll
    for (int j = 0; j < 4; j++) {
      int kv = (kq + j * 8) * 4;
      float4 xv = make_float4(0.f, 0.f, 0.f, 0.f);
      float4 mv = make_float4(0.f, 0.f, 0.f, 0.f);
      if (rvalid) {
        xv = *reinterpret_cast<const float4*>(xr + kv);
        mv = *reinterpret_cast<const float4*>(mr + kv);
      }
      XT[kv + 0][srow] = xv.x; XT[kv + 1][srow] = xv.y;
      XT[kv + 2][srow] = xv.z; XT[kv + 3][srow] = xv.w;
      MT[kv + 0][srow] = mv.x; MT[kv + 1][srow] = mv.y;
      MT[kv + 2][srow] = mv.z; MT[kv + 3][srow] = mv.w;
    }
  }
  __syncthreads();

  int tc = tid & 31;
  int tr = tid >> 5;

  float acc[4][4] = {{0.f}};

#pragma unroll 4
  for (int k = 0; k < DD; k++) {
    float4 wv = *reinterpret_cast<const float4*>(W1T + k * DD + tc * 4);
    float4 xv = *reinterpret_cast<const float4*>(&XT[k][tr * 4]);
    float x[4] = {xv.x, xv.y, xv.z, xv.w};
    float w[4] = {wv.x, wv.y, wv.z, wv.w};
#pragma unroll
    for (int ri = 0; ri < 4; ri++)
#pragma unroll
      for (int cj = 0; cj < 4; cj++) acc[ri][cj] += x[ri] * w[cj];
  }
#pragma unroll 4
  for (int k = 0; k < DD; k++) {
    float4 wv = *reinterpret_cast<const float4*>(W2T + k * DD + tc * 4);
    float4 xv = *reinterpret_cast<const float4*>(&MT[k][tr * 4]);
    float x[4] = {xv.x, xv.y, xv.z, xv.w};
    float w[4] = {wv.x, wv.y, wv.z, wv.w};
#pragma unroll
    for (int ri = 0; ri < 4; ri++)
#pragma unroll
      for (int cj = 0; cj < 4; cj++) acc[ri][cj] += x[ri] * w[cj];
  }

  float4 b1v = *reinterpret_cast<const float4*>(b1 + tc * 4);
  float4 b2v = *reinterpret_cast<const float4*>(b2 + tc * 4);
  float bias[4] = {b1v.x + b2v.x, b1v.y + b2v.y, b1v.z + b2v.z, b1v.w + b2v.w};

#pragma unroll
  for (int ri = 0; ri < 4; ri++) {
    float v[4];
    float ss = 0.f;
#pragma unroll
    for (int cj = 0; cj < 4; cj++) {
      float h = acc[ri][cj] + bias[cj];
      h = (h > 0.f) ? h : 0.2f * h;
      v[cj] = h;
      ss += h * h;
    }
#pragma unroll
    for (int m = 1; m < 32; m <<= 1) ss += __shfl_xor(ss, m);
    float inv = 1.0f / fmaxf(sqrtf(ss), 1e-12f);
    int row = row0 + tr * 4 + ri;
    if (row < nrows) {
      float4 ov = make_float4(v[0] * inv, v[1] * inv, v[2] * inv, v[3] * inv);
      *reinterpret_cast<float4*>(o + (size_t)row * DD + tc * 4) = ov;
    }
  }
}

// ---------------------------------------------------------------------------
extern "C" void kernel_launch(void* const* d_in, const int* in_sizes, int n_in,
                              void* d_out, int out_size, void* d_ws, size_t ws_size,
                              hipStream_t stream) {
  const float* fu  = (const float*)d_in[0];
  const float* fi  = (const float*)d_in[1];
  const float* nu  = (const float*)d_in[2];
  const float* ni  = (const float*)d_in[3];
  const float* nui = (const float*)d_in[4];
  const float* niu = (const float*)d_in[5];
  const float* W1  = (const float*)d_in[6];
  const float* b1  = (const float*)d_in[7];
  const float* W2  = (const float*)d_in[8];
  const float* b2  = (const float*)d_in[9];
  const int* eu    = (const int*)d_in[10];
  const int* ei    = (const int*)d_in[11];
  float* out = (float*)d_out;
  float* ws = (float*)d_ws;

  size_t off_f = 0;
  float* Xu = ws + off_f; off_f += (size_t)NU_ * DD;
  float* Mu = ws + off_f; off_f += (size_t)NU_ * DD;
  float* Xi = ws + off_f; off_f += (size_t)NI_ * DD;
  float* Mi = ws + off_f; off_f += (size_t)NI_ * DD;
  float* W1T = ws + off_f; off_f += (size_t)DD * DD;
  float* W2T = ws + off_f; off_f += (size_t)DD * DD;
  int* deg  = (int*)(ws + off_f); off_f += NT_;
  int* offs = (int*)(ws + off_f); off_f += NT_;
  int* cur  = (int*)(ws + off_f); off_f += NT_;
  int* bsum = (int*)(ws + off_f); off_f += 128;
  int2* adj = (int2*)(ws + off_f); off_f += (size_t)2 * E_ * 2;  // 2E int2 = 4E floats

  hipMemsetAsync(deg, 0, NT_ * sizeof(int), stream);

  wtrans_kernel<<<(DD * DD + 255) / 256, 256, 0, stream>>>(W1, W2, W1T, W2T);

  count_deg_kernel<<<(E_ + 255) / 256, 256, 0, stream>>>(eu, ei, deg);
  scan1_kernel<<<NSCAN, 256, 0, stream>>>(deg, offs, bsum);
  scan2_kernel<<<1, 64, 0, stream>>>(bsum);
  scan3_kernel<<<(NT_ + 255) / 256, 256, 0, stream>>>(offs, cur, bsum);
  fill_adj_kernel<<<(E_ + 255) / 256, 256, 0, stream>>>(eu, ei, nui, niu, cur, adj);

  gather_kernel<<<(NT_ + 7) / 8, 256, 0, stream>>>(
      fu, fi, nu, ni, offs, deg, adj, Xu, Mu, Xi, Mi);

  int nblk_u = (NU_ + 31) / 32;
  int nblk_i = (NI_ + 31) / 32;
  gemm_post_kernel<<<nblk_u + nblk_i, 256, 0, stream>>>(
      Xu, Mu, Xi, Mi, W1T, W2T, b1, b2, out, nblk_u);
}

// Round 3
// 284.638 us; speedup vs baseline: 14.7929x; 1.6408x over previous
//
#include <hip/hip_runtime.h>

#define NU_ 100000
#define NI_ 50000
#define E_  600000
#define DD  128
#define NT_ (NU_ + NI_)
#define NTILE_U (NU_ / 16)    // 6250
#define NTILE_ALL (NT_ / 16)  // 9375
#define SCAN_BLK 2048
#define NSCAN ((NT_ + SCAN_BLK - 1) / SCAN_BLK)  // 74

typedef short bf16x8 __attribute__((ext_vector_type(8)));
typedef float f32x4 __attribute__((ext_vector_type(4)));
typedef unsigned short u16x8 __attribute__((ext_vector_type(8)));

__device__ __forceinline__ unsigned short f2bf(float x) {
  unsigned u = __float_as_uint(x);
  return (unsigned short)((u + 0x7FFFu + ((u >> 16) & 1u)) >> 16);  // RNE
}
__device__ __forceinline__ float bf2f(unsigned short h) {
  return __uint_as_float((unsigned)h << 16);
}

// ---------------------------------------------------------------------------
// Pack W1,W2 into mfma_f32_16x16x32_bf16 B-fragment order:
// Bp[w][nt][kt][lane][j] = W[nt*16 + (lane&15)][kt*32 + (lane>>4)*8 + j]
// (B[k][n] = W^T[k][n]; lane holds B[(l>>4)*8+j][l&15])
// ---------------------------------------------------------------------------
__global__ __launch_bounds__(256) void pack_kernel(
    const float* __restrict__ W1, const float* __restrict__ W2,
    unsigned short* __restrict__ Bp) {
  int t = blockIdx.x * 256 + threadIdx.x;  // 4096 total
  if (t >= 4096) return;
  int w = t >> 11;
  int l = t & 63;
  int kt = (t >> 6) & 3;
  int nt = (t >> 8) & 7;
  const float* W = w ? W2 : W1;
  int n = nt * 16 + (l & 15);
  int k0 = kt * 32 + (l >> 4) * 8;
  unsigned short* dst = Bp + (size_t)t * 8;
#pragma unroll
  for (int j = 0; j < 8; j++) dst[j] = f2bf(W[n * DD + k0 + j]);
}

// ---------------------------------------------------------------------------
// f32 -> bf16 table conversion (8 elems/thread)
// ---------------------------------------------------------------------------
__global__ __launch_bounds__(256) void tobf_kernel(
    const float* __restrict__ src, unsigned short* __restrict__ dst, int n8) {
  int t = blockIdx.x * 256 + threadIdx.x;
  if (t >= n8) return;
  const float4 v0 = reinterpret_cast<const float4*>(src)[t * 2];
  const float4 v1 = reinterpret_cast<const float4*>(src)[t * 2 + 1];
  u16x8 o;
  o[0] = f2bf(v0.x); o[1] = f2bf(v0.y); o[2] = f2bf(v0.z); o[3] = f2bf(v0.w);
  o[4] = f2bf(v1.x); o[5] = f2bf(v1.y); o[6] = f2bf(v1.z); o[7] = f2bf(v1.w);
  reinterpret_cast<u16x8*>(dst)[t] = o;
}

// ---------------------------------------------------------------------------
// CSR build
// ---------------------------------------------------------------------------
__global__ __launch_bounds__(256) void count_deg_kernel(
    const int* __restrict__ eu, const int* __restrict__ ei, int* __restrict__ deg) {
  int e = blockIdx.x * 256 + threadIdx.x;
  if (e >= E_) return;
  atomicAdd(&deg[eu[e]], 1);
  atomicAdd(&deg[NU_ + ei[e]], 1);
}

__global__ __launch_bounds__(256) void scan1_kernel(
    const int* __restrict__ deg, int* __restrict__ off, int* __restrict__ bsum) {
  __shared__ int ts[256];
  int tid = threadIdx.x;
  int base = blockIdx.x * SCAN_BLK + tid * 8;
  int v[8];
  int s = 0;
#pragma unroll
  for (int j = 0; j < 8; j++) {
    v[j] = s;
    int idx = base + j;
    s += (idx < NT_) ? deg[idx] : 0;
  }
  ts[tid] = s;
  __syncthreads();
  for (int ofs = 1; ofs < 256; ofs <<= 1) {
    int add = (tid >= ofs) ? ts[tid - ofs] : 0;
    __syncthreads();
    ts[tid] += add;
    __syncthreads();
  }
  int texcl = ts[tid] - s;
#pragma unroll
  for (int j = 0; j < 8; j++) {
    int idx = base + j;
    if (idx < NT_) off[idx] = texcl + v[j];
  }
  if (tid == 255) bsum[blockIdx.x] = ts[255];
}

__global__ void scan2_kernel(int* __restrict__ bsum) {
  if (threadIdx.x == 0) {
    int s = 0;
    for (int n = 0; n < NSCAN; n++) {
      int t = bsum[n];
      bsum[n] = s;
      s += t;
    }
  }
}

__global__ __launch_bounds__(256) void scan3_kernel(
    int* __restrict__ off, int* __restrict__ cur, const int* __restrict__ bsum) {
  int i = blockIdx.x * 256 + threadIdx.x;
  if (i >= NT_) return;
  int v = off[i] + bsum[i >> 11];
  off[i] = v;
  cur[i] = v;
}

__global__ __launch_bounds__(256) void fill_adj_kernel(
    const int* __restrict__ eu, const int* __restrict__ ei,
    const float* __restrict__ nui, const float* __restrict__ niu,
    int* __restrict__ cur, int2* __restrict__ adj) {
  int e = blockIdx.x * 256 + threadIdx.x;
  if (e >= E_) return;
  int u = eu[e], i = ei[e];
  int pu = atomicAdd(&cur[u], 1);
  adj[pu] = make_int2(i, __float_as_int(niu[e]));
  int pi = atomicAdd(&cur[NU_ + i], 1);
  adj[pi] = make_int2(u, __float_as_int(nui[e]));
}

// ---------------------------------------------------------------------------
// Gather (bf16 neighbor rows, f32 accumulate, bf16 X/M out).
// 32 lanes/node, 4 dims/lane. Every row written once.
//   X[g] = feat[g] + sum_n fnb[idx]*w
//   M[g] = feat[g]*s_own .* sum_n fnb[idx]*s_nb[idx]
// ---------------------------------------------------------------------------
__global__ __launch_bounds__(256) void gather_kernel(
    const float* __restrict__ fu, const float* __restrict__ fi,
    const unsigned short* __restrict__ fub, const unsigned short* __restrict__ fib,
    const float* __restrict__ nu, const float* __restrict__ ni,
    const int* __restrict__ off, const int* __restrict__ deg,
    const int2* __restrict__ adj,
    unsigned short* __restrict__ Xu, unsigned short* __restrict__ Mu,
    unsigned short* __restrict__ Xi, unsigned short* __restrict__ Mi) {
  int g = blockIdx.x * 8 + (threadIdx.x >> 5);
  if (g >= NT_) return;
  int lane = threadIdx.x & 31;
  bool isU = g < NU_;
  const unsigned short* nbF = isU ? fib : fub;
  const float* nbS = isU ? ni : nu;
  int n = off[g];
  int end = n + deg[g];

  float aA[4] = {0.f, 0.f, 0.f, 0.f};
  float aM[4] = {0.f, 0.f, 0.f, 0.f};

  // 2-deep unroll so the two (adj -> snb -> row) chains overlap
  for (; n + 2 <= end; n += 2) {
    int2 a0 = adj[n];
    int2 a1 = adj[n + 1];
    float w0 = __int_as_float(a0.y), s0 = nbS[a0.x];
    float w1 = __int_as_float(a1.y), s1 = nbS[a1.x];
    ushort4 f0 = *reinterpret_cast<const ushort4*>(nbF + (size_t)a0.x * DD + lane * 4);
    ushort4 f1 = *reinterpret_cast<const ushort4*>(nbF + (size_t)a1.x * DD + lane * 4);
    float g0[4] = {bf2f(f0.x), bf2f(f0.y), bf2f(f0.z), bf2f(f0.w)};
    float g1[4] = {bf2f(f1.x), bf2f(f1.y), bf2f(f1.z), bf2f(f1.w)};
#pragma unroll
    for (int j = 0; j < 4; j++) {
      aA[j] += g0[j] * w0 + g1[j] * w1;
      aM[j] += g0[j] * s0 + g1[j] * s1;
    }
  }
  if (n < end) {
    int2 a0 = adj[n];
    float w0 = __int_as_float(a0.y), s0 = nbS[a0.x];
    ushort4 f0 = *reinterpret_cast<const ushort4*>(nbF + (size_t)a0.x * DD + lane * 4);
    float g0[4] = {bf2f(f0.x), bf2f(f0.y), bf2f(f0.z), bf2f(f0.w)};
#pragma unroll
    for (int j = 0; j < 4; j++) {
      aA[j] += g0[j] * w0;
      aM[j] += g0[j] * s0;
    }
  }

  int lrow = isU ? g : g - NU_;
  const float* own = (isU ? fu : fi) + (size_t)lrow * DD + lane * 4;
  float sown = isU ? nu[lrow] : ni[lrow];
  unsigned short* X = (isU ? Xu : Xi) + (size_t)lrow * DD + lane * 4;
  unsigned short* M = (isU ? Mu : Mi) + (size_t)lrow * DD + lane * 4;

  float4 fo = *reinterpret_cast<const float4*>(own);
  float fv[4] = {fo.x, fo.y, fo.z, fo.w};
  ushort4 xv, mv;
  xv.x = f2bf(fv[0] + aA[0]); xv.y = f2bf(fv[1] + aA[1]);
  xv.z = f2bf(fv[2] + aA[2]); xv.w = f2bf(fv[3] + aA[3]);
  mv.x = f2bf(fv[0] * sown * aM[0]); mv.y = f2bf(fv[1] * sown * aM[1]);
  mv.z = f2bf(fv[2] * sown * aM[2]); mv.w = f2bf(fv[3] * sown * aM[3]);
  *reinterpret_cast<ushort4*>(X) = xv;
  *reinterpret_cast<ushort4*>(M) = mv;
}

// ---------------------------------------------------------------------------
// MFMA GEMM + fused epilogue.
// 512 threads = 8 waves; each wave owns one 16-row tile x 128 cols.
// acc[nt] (nt=0..7) 16x16 tiles; K=128 via 4 kt steps of 32; two GEMMs
// (X@W1^T + M@W2^T) accumulate into the same acc.
// B fragments staged in LDS (64KB, lane-contiguous ds_read_b128).
// ---------------------------------------------------------------------------
__global__ __launch_bounds__(512) void gemm_mfma_kernel(
    const unsigned short* __restrict__ Xu, const unsigned short* __restrict__ Mu,
    const unsigned short* __restrict__ Xi, const unsigned short* __restrict__ Mi,
    const unsigned short* __restrict__ Bp,
    const float* __restrict__ b1, const float* __restrict__ b2,
    float* __restrict__ out) {
  __shared__ __align__(16) unsigned short Bs[32768];  // 64 KB

  {  // stage packed B (both W) into LDS
    const float4* src = reinterpret_cast<const float4*>(Bp);
    float4* dst = reinterpret_cast<float4*>(Bs);
    for (int i = threadIdx.x; i < 4096; i += 512) dst[i] = src[i];
  }
  __syncthreads();

  int wid = threadIdx.x >> 6;
  int lane = threadIdx.x & 63;
  int gt = blockIdx.x * 8 + wid;
  if (gt >= NTILE_ALL) return;

  const unsigned short* X;
  const unsigned short* M;
  float* o;
  int row0;
  if (gt < NTILE_U) {
    X = Xu; M = Mu; o = out; row0 = gt * 16;
  } else {
    X = Xi; M = Mi; o = out + (size_t)NU_ * DD; row0 = (gt - NTILE_U) * 16;
  }

  int lm = lane & 15, lh = lane >> 4;
  const unsigned short* xb = X + (size_t)(row0 + lm) * DD + lh * 8;
  const unsigned short* mb = M + (size_t)(row0 + lm) * DD + lh * 8;

  bf16x8 a1[4], a2[4];
#pragma unroll
  for (int kt = 0; kt < 4; kt++) {
    a1[kt] = *reinterpret_cast<const bf16x8*>(xb + kt * 32);
    a2[kt] = *reinterpret_cast<const bf16x8*>(mb + kt * 32);
  }

  f32x4 acc[8];
#pragma unroll
  for (int nt = 0; nt < 8; nt++) {
    f32x4 c = {0.f, 0.f, 0.f, 0.f};
#pragma unroll
    for (int kt = 0; kt < 4; kt++) {
      bf16x8 bf1 = *reinterpret_cast<const bf16x8*>(Bs + ((size_t)((0 * 8 + nt) * 4 + kt) * 64 + lane) * 8);
      c = __builtin_amdgcn_mfma_f32_16x16x32_bf16(a1[kt], bf1, c, 0, 0, 0);
      bf16x8 bf2 = *reinterpret_cast<const bf16x8*>(Bs + ((size_t)((1 * 8 + nt) * 4 + kt) * 64 + lane) * 8);
      c = __builtin_amdgcn_mfma_f32_16x16x32_bf16(a2[kt], bf2, c, 0, 0, 0);
    }
    acc[nt] = c;
  }

  // epilogue: bias -> leaky relu -> row L2 norm -> store
  // C layout: row = row0 + lh*4 + r, col = nt*16 + lm
  float h[8][4];
  float ss[4] = {0.f, 0.f, 0.f, 0.f};
#pragma unroll
  for (int nt = 0; nt < 8; nt++) {
    float bb = b1[nt * 16 + lm] + b2[nt * 16 + lm];
#pragma unroll
    for (int r = 0; r < 4; r++) {
      float v = acc[nt][r] + bb;
      v = (v > 0.f) ? v : 0.2f * v;
      h[nt][r] = v;
      ss[r] += v * v;
    }
  }
#pragma unroll
  for (int r = 0; r < 4; r++) {
#pragma unroll
    for (int m = 1; m < 16; m <<= 1) ss[r] += __shfl_xor(ss[r], m);
  }
  float inv[4];
#pragma unroll
  for (int r = 0; r < 4; r++) inv[r] = 1.0f / fmaxf(sqrtf(ss[r]), 1e-12f);

#pragma unroll
  for (int nt = 0; nt < 8; nt++) {
#pragma unroll
    for (int r = 0; r < 4; r++) {
      o[(size_t)(row0 + lh * 4 + r) * DD + nt * 16 + lm] = h[nt][r] * inv[r];
    }
  }
}

// ---------------------------------------------------------------------------
extern "C" void kernel_launch(void* const* d_in, const int* in_sizes, int n_in,
                              void* d_out, int out_size, void* d_ws, size_t ws_size,
                              hipStream_t stream) {
  const float* fu  = (const float*)d_in[0];
  const float* fi  = (const float*)d_in[1];
  const float* nu  = (const float*)d_in[2];
  const float* ni  = (const float*)d_in[3];
  const float* nui = (const float*)d_in[4];
  const float* niu = (const float*)d_in[5];
  const float* W1  = (const float*)d_in[6];
  const float* b1  = (const float*)d_in[7];
  const float* W2  = (const float*)d_in[8];
  const float* b2  = (const float*)d_in[9];
  const int* eu    = (const int*)d_in[10];
  const int* ei    = (const int*)d_in[11];
  float* out = (float*)d_out;
  char* ws = (char*)d_ws;

  size_t off_b = 0;
  auto alloc = [&](size_t bytes) {
    char* p = ws + off_b;
    off_b += (bytes + 255) & ~(size_t)255;
    return p;
  };
  unsigned short* Xub = (unsigned short*)alloc((size_t)NU_ * DD * 2);
  unsigned short* Mub = (unsigned short*)alloc((size_t)NU_ * DD * 2);
  unsigned short* Xib = (unsigned short*)alloc((size_t)NI_ * DD * 2);
  unsigned short* Mib = (unsigned short*)alloc((size_t)NI_ * DD * 2);
  unsigned short* fub = (unsigned short*)alloc((size_t)NU_ * DD * 2);
  unsigned short* fib = (unsigned short*)alloc((size_t)NI_ * DD * 2);
  unsigned short* Bp  = (unsigned short*)alloc(4096 * 8 * 2);
  int* deg  = (int*)alloc(NT_ * 4);
  int* offs = (int*)alloc(NT_ * 4);
  int* cur  = (int*)alloc(NT_ * 4);
  int* bsum = (int*)alloc(128 * 4);
  int2* adj = (int2*)alloc((size_t)2 * E_ * 8);

  hipMemsetAsync(deg, 0, NT_ * sizeof(int), stream);

  pack_kernel<<<16, 256, 0, stream>>>(W1, W2, Bp);
  tobf_kernel<<<(NU_ * DD / 8 + 255) / 256, 256, 0, stream>>>(fu, fub, NU_ * DD / 8);
  tobf_kernel<<<(NI_ * DD / 8 + 255) / 256, 256, 0, stream>>>(fi, fib, NI_ * DD / 8);

  count_deg_kernel<<<(E_ + 255) / 256, 256, 0, stream>>>(eu, ei, deg);
  scan1_kernel<<<NSCAN, 256, 0, stream>>>(deg, offs, bsum);
  scan2_kernel<<<1, 64, 0, stream>>>(bsum);
  scan3_kernel<<<(NT_ + 255) / 256, 256, 0, stream>>>(offs, cur, bsum);
  fill_adj_kernel<<<(E_ + 255) / 256, 256, 0, stream>>>(eu, ei, nui, niu, cur, adj);

  gather_kernel<<<(NT_ + 7) / 8, 256, 0, stream>>>(
      fu, fi, fub, fib, nu, ni, offs, deg, adj, Xub, Mub, Xib, Mib);

  gemm_mfma_kernel<<<(NTILE_ALL + 7) / 8, 512, 0, stream>>>(
      Xub, Mub, Xib, Mib, Bp, b1, b2, out);
}

// Round 4
// 219.119 us; speedup vs baseline: 19.2162x; 1.2990x over previous
//
#include <hip/hip_runtime.h>

#define NU_ 100000
#define NI_ 50000
#define E_  600000
#define DD  128
#define NT_ (NU_ + NI_)
#define NTILE_U (NU_ / 16)    // 6250
#define NTILE_ALL (NT_ / 16)  // 9375

// bucketed CSR build
#define NBKT ((NT_ + 127) >> 7)        // 1172 buckets of 128 nodes
#define SBLK 8192                       // edges per scatter block
#define NSB ((E_ + SBLK - 1) / SBLK)    // 74
#define NL (NBKT * NSB)                 // 86728 (bucket,block) cells
#define NSCB ((NL + 2047) / 2048)       // 43 scan blocks
#define MAXE 3072                       // max entries per bucket (mean 1024, worst ~1850)

typedef short bf16x8 __attribute__((ext_vector_type(8)));
typedef float f32x4 __attribute__((ext_vector_type(4)));
typedef unsigned short u16x8 __attribute__((ext_vector_type(8)));

__device__ __forceinline__ unsigned short f2bf(float x) {
  unsigned u = __float_as_uint(x);
  return (unsigned short)((u + 0x7FFFu + ((u >> 16) & 1u)) >> 16);  // RNE
}
__device__ __forceinline__ float bf2f(unsigned short h) {
  return __uint_as_float((unsigned)h << 16);
}

// logical scan index L = bkt*NSB + sb  <->  storage idx = sb*NBKT + bkt
__device__ __forceinline__ int sidx(int L) {
  int bkt = L / NSB;
  int sb = L - bkt * NSB;
  return sb * NBKT + bkt;
}

// ---------------------------------------------------------------------------
// Pack W1,W2 into mfma_f32_16x16x32_bf16 B-fragment order.
// ---------------------------------------------------------------------------
__global__ __launch_bounds__(256) void pack_kernel(
    const float* __restrict__ W1, const float* __restrict__ W2,
    unsigned short* __restrict__ Bp) {
  int t = blockIdx.x * 256 + threadIdx.x;  // 4096 total
  if (t >= 4096) return;
  int w = t >> 11;
  int l = t & 63;
  int kt = (t >> 6) & 3;
  int nt = (t >> 8) & 7;
  const float* W = w ? W2 : W1;
  int n = nt * 16 + (l & 15);
  int k0 = kt * 32 + (l >> 4) * 8;
  unsigned short* dst = Bp + (size_t)t * 8;
#pragma unroll
  for (int j = 0; j < 8; j++) dst[j] = f2bf(W[n * DD + k0 + j]);
}

// ---------------------------------------------------------------------------
// f32 -> bf16 feature tables
// ---------------------------------------------------------------------------
__global__ __launch_bounds__(256) void tobf_kernel(
    const float* __restrict__ src, unsigned short* __restrict__ dst, int n8) {
  int t = blockIdx.x * 256 + threadIdx.x;
  if (t >= n8) return;
  const float4 v0 = reinterpret_cast<const float4*>(src)[t * 2];
  const float4 v1 = reinterpret_cast<const float4*>(src)[t * 2 + 1];
  u16x8 o;
  o[0] = f2bf(v0.x); o[1] = f2bf(v0.y); o[2] = f2bf(v0.z); o[3] = f2bf(v0.w);
  o[4] = f2bf(v1.x); o[5] = f2bf(v1.y); o[6] = f2bf(v1.z); o[7] = f2bf(v1.w);
  reinterpret_cast<u16x8*>(dst)[t] = o;
}

// ---------------------------------------------------------------------------
// Pass A: per-(scatter-block, bucket) histogram. LDS counters, coalesced out.
// ---------------------------------------------------------------------------
__global__ __launch_bounds__(512) void hist_kernel(
    const int* __restrict__ eu, const int* __restrict__ ei, int* __restrict__ hist) {
  __shared__ int cnt[NBKT];
  int sb = blockIdx.x, tid = threadIdx.x;
  for (int k = tid; k < NBKT; k += 512) cnt[k] = 0;
  __syncthreads();
#pragma unroll
  for (int j = 0; j < SBLK / 512; j++) {
    int e = sb * SBLK + j * 512 + tid;
    if (e < E_) {
      atomicAdd(&cnt[eu[e] >> 7], 1);
      atomicAdd(&cnt[(NU_ + ei[e]) >> 7], 1);
    }
  }
  __syncthreads();
  for (int k = tid; k < NBKT; k += 512) hist[sb * NBKT + k] = cnt[k];
}

// ---------------------------------------------------------------------------
// Scan over NL cells in logical (bucket-major) order.
// ---------------------------------------------------------------------------
__global__ __launch_bounds__(256) void scanA_kernel(
    const int* __restrict__ hist, int* __restrict__ off, int* __restrict__ bsum) {
  __shared__ int ts[256];
  int tid = threadIdx.x;
  int base = blockIdx.x * 2048 + tid * 8;
  int v[8];
  int s = 0;
#pragma unroll
  for (int j = 0; j < 8; j++) {
    v[j] = s;
    int L = base + j;
    s += (L < NL) ? hist[sidx(L)] : 0;
  }
  ts[tid] = s;
  __syncthreads();
  for (int ofs = 1; ofs < 256; ofs <<= 1) {
    int add = (tid >= ofs) ? ts[tid - ofs] : 0;
    __syncthreads();
    ts[tid] += add;
    __syncthreads();
  }
  int texcl = ts[tid] - s;
#pragma unroll
  for (int j = 0; j < 8; j++) {
    int L = base + j;
    if (L < NL) off[sidx(L)] = texcl + v[j];
  }
  if (tid == 255) bsum[blockIdx.x] = ts[255];
}

__global__ void scanB_kernel(int* __restrict__ bsum) {
  if (threadIdx.x == 0) {
    int s = 0;
    for (int n = 0; n < NSCB; n++) {
      int t = bsum[n];
      bsum[n] = s;
      s += t;
    }
  }
}

__global__ __launch_bounds__(256) void scanC_kernel(
    int* __restrict__ off, const int* __restrict__ bsum) {
  int L = blockIdx.x * 256 + threadIdx.x;
  if (L >= NL) return;
  off[sidx(L)] += bsum[L >> 11];
}

// ---------------------------------------------------------------------------
// Pass C: scatter edges into bucket-sorted array. Within a bucket, each
// block's entries are contiguous -> long write runs, ~1.3x amplification.
// entry.x = (g_local<<20) | neighbor_idx ; entry.y = weight bits
// ---------------------------------------------------------------------------
__global__ __launch_bounds__(512) void scatter_kernel(
    const int* __restrict__ eu, const int* __restrict__ ei,
    const float* __restrict__ nui, const float* __restrict__ niu,
    const int* __restrict__ off, int2* __restrict__ binned) {
  __shared__ int cur[NBKT];
  int sb = blockIdx.x, tid = threadIdx.x;
  for (int k = tid; k < NBKT; k += 512) cur[k] = off[sb * NBKT + k];
  __syncthreads();
#pragma unroll
  for (int j = 0; j < SBLK / 512; j++) {
    int e = sb * SBLK + j * 512 + tid;
    if (e < E_) {
      int u = eu[e], i = ei[e];
      int gi = NU_ + i;
      int s1 = atomicAdd(&cur[u >> 7], 1);
      binned[s1] = make_int2(((u & 127) << 20) | i, __float_as_int(niu[e]));
      int s2 = atomicAdd(&cur[gi >> 7], 1);
      binned[s2] = make_int2(((gi & 127) << 20) | u, __float_as_int(nui[e]));
    }
  }
}

// ---------------------------------------------------------------------------
// Pass D: per-bucket gather. Build 128-node CSR in LDS, then 8 waves x 16
// nodes; 2 neighbors per step (half-wave each), shfl_xor(32) combine.
//   X[g] = feat[g] + sum fnb[idx]*w
//   M[g] = feat[g]*s_own .* sum fnb[idx]*s_nb[idx]
// ---------------------------------------------------------------------------
__global__ __launch_bounds__(512) void gatherb_kernel(
    const float* __restrict__ fu, const float* __restrict__ fi,
    const unsigned short* __restrict__ fub, const unsigned short* __restrict__ fib,
    const float* __restrict__ nu, const float* __restrict__ ni,
    const int* __restrict__ off, const int2* __restrict__ binned,
    unsigned short* __restrict__ Xu, unsigned short* __restrict__ Mu,
    unsigned short* __restrict__ Xi, unsigned short* __restrict__ Mi) {
  __shared__ int2 ent[MAXE];
  __shared__ int ncnt[128];
  __shared__ int nstart[129];
  __shared__ int ncur[128];

  int bkt = blockIdx.x, tid = threadIdx.x;
  int bs = off[bkt];  // storage idx (sb=0, bkt) == bucket start
  int be = (bkt + 1 < NBKT) ? off[bkt + 1] : 2 * E_;
  int cnt = be - bs;
  if (cnt > MAXE) cnt = MAXE;  // statistically impossible

  if (tid < 128) ncnt[tid] = 0;
  __syncthreads();
  for (int k = tid; k < cnt; k += 512)
    atomicAdd(&ncnt[(binned[bs + k].x >> 20) & 127], 1);
  __syncthreads();

  if (tid == 0) nstart[0] = 0;
  if (tid < 128) nstart[tid + 1] = ncnt[tid];
  __syncthreads();
  for (int ofs = 1; ofs < 128; ofs <<= 1) {
    int v = 0;
    if (tid < 128 && tid >= ofs) v = nstart[tid + 1 - ofs];
    __syncthreads();
    if (tid < 128) nstart[tid + 1] += v;
    __syncthreads();
  }
  if (tid < 128) ncur[tid] = nstart[tid];
  __syncthreads();

  for (int k = tid; k < cnt; k += 512) {
    int2 a = binned[bs + k];
    int slot = atomicAdd(&ncur[(a.x >> 20) & 127], 1);
    ent[slot] = a;
  }
  __syncthreads();

  int wid = tid >> 6, lane = tid & 63;
  int half = lane >> 5, sub = lane & 31;

  for (int nn = 0; nn < 16; nn++) {
    int gl = wid * 16 + nn;
    int g = bkt * 128 + gl;
    if (g >= NT_) break;
    bool isU = g < NU_;
    const unsigned short* nbF = isU ? fib : fub;
    const float* nbS = isU ? ni : nu;
    int cs = nstart[gl], ce = nstart[gl + 1];

    float aA[4] = {0.f, 0.f, 0.f, 0.f};
    float aM[4] = {0.f, 0.f, 0.f, 0.f};
    for (int j = cs + half; j < ce; j += 2) {
      int2 a = ent[j];
      int idx = a.x & 0xFFFFF;
      float w = __int_as_float(a.y);
      float snb = nbS[idx];
      ushort4 f = *reinterpret_cast<const ushort4*>(nbF + (size_t)idx * DD + sub * 4);
      float r[4] = {bf2f(f.x), bf2f(f.y), bf2f(f.z), bf2f(f.w)};
#pragma unroll
      for (int d = 0; d < 4; d++) {
        aA[d] += r[d] * w;
        aM[d] += r[d] * snb;
      }
    }
#pragma unroll
    for (int d = 0; d < 4; d++) {
      aA[d] += __shfl_xor(aA[d], 32);
      aM[d] += __shfl_xor(aM[d], 32);
    }

    int lrow = isU ? g : g - NU_;
    const float* ownp = (isU ? fu : fi) + (size_t)lrow * DD + sub * 4;
    float so = isU ? nu[lrow] : ni[lrow];
    float4 fo = *reinterpret_cast<const float4*>(ownp);
    if (half == 0) {
      ushort4 xv;
      xv.x = f2bf(fo.x + aA[0]); xv.y = f2bf(fo.y + aA[1]);
      xv.z = f2bf(fo.z + aA[2]); xv.w = f2bf(fo.w + aA[3]);
      *reinterpret_cast<ushort4*>(((isU ? Xu : Xi) + (size_t)lrow * DD + sub * 4)) = xv;
    } else {
      ushort4 mv;
      mv.x = f2bf(fo.x * so * aM[0]); mv.y = f2bf(fo.y * so * aM[1]);
      mv.z = f2bf(fo.z * so * aM[2]); mv.w = f2bf(fo.w * so * aM[3]);
      *reinterpret_cast<ushort4*>(((isU ? Mu : Mi) + (size_t)lrow * DD + sub * 4)) = mv;
    }
  }
}

// ---------------------------------------------------------------------------
// MFMA GEMM + fused epilogue (unchanged from round 3).
// ---------------------------------------------------------------------------
__global__ __launch_bounds__(512) void gemm_mfma_kernel(
    const unsigned short* __restrict__ Xu, const unsigned short* __restrict__ Mu,
    const unsigned short* __restrict__ Xi, const unsigned short* __restrict__ Mi,
    const unsigned short* __restrict__ Bp,
    const float* __restrict__ b1, const float* __restrict__ b2,
    float* __restrict__ out) {
  __shared__ __align__(16) unsigned short Bs[32768];  // 64 KB

  {
    const float4* src = reinterpret_cast<const float4*>(Bp);
    float4* dst = reinterpret_cast<float4*>(Bs);
    for (int i = threadIdx.x; i < 4096; i += 512) dst[i] = src[i];
  }
  __syncthreads();

  int wid = threadIdx.x >> 6;
  int lane = threadIdx.x & 63;
  int gt = blockIdx.x * 8 + wid;
  if (gt >= NTILE_ALL) return;

  const unsigned short* X;
  const unsigned short* M;
  float* o;
  int row0;
  if (gt < NTILE_U) {
    X = Xu; M = Mu; o = out; row0 = gt * 16;
  } else {
    X = Xi; M = Mi; o = out + (size_t)NU_ * DD; row0 = (gt - NTILE_U) * 16;
  }

  int lm = lane & 15, lh = lane >> 4;
  const unsigned short* xb = X + (size_t)(row0 + lm) * DD + lh * 8;
  const unsigned short* mb = M + (size_t)(row0 + lm) * DD + lh * 8;

  bf16x8 a1[4], a2[4];
#pragma unroll
  for (int kt = 0; kt < 4; kt++) {
    a1[kt] = *reinterpret_cast<const bf16x8*>(xb + kt * 32);
    a2[kt] = *reinterpret_cast<const bf16x8*>(mb + kt * 32);
  }

  f32x4 acc[8];
#pragma unroll
  for (int nt = 0; nt < 8; nt++) {
    f32x4 c = {0.f, 0.f, 0.f, 0.f};
#pragma unroll
    for (int kt = 0; kt < 4; kt++) {
      bf16x8 bf1 = *reinterpret_cast<const bf16x8*>(Bs + ((size_t)((0 * 8 + nt) * 4 + kt) * 64 + lane) * 8);
      c = __builtin_amdgcn_mfma_f32_16x16x32_bf16(a1[kt], bf1, c, 0, 0, 0);
      bf16x8 bf2 = *reinterpret_cast<const bf16x8*>(Bs + ((size_t)((1 * 8 + nt) * 4 + kt) * 64 + lane) * 8);
      c = __builtin_amdgcn_mfma_f32_16x16x32_bf16(a2[kt], bf2, c, 0, 0, 0);
    }
    acc[nt] = c;
  }

  float h[8][4];
  float ss[4] = {0.f, 0.f, 0.f, 0.f};
#pragma unroll
  for (int nt = 0; nt < 8; nt++) {
    float bb = b1[nt * 16 + lm] + b2[nt * 16 + lm];
#pragma unroll
    for (int r = 0; r < 4; r++) {
      float v = acc[nt][r] + bb;
      v = (v > 0.f) ? v : 0.2f * v;
      h[nt][r] = v;
      ss[r] += v * v;
    }
  }
#pragma unroll
  for (int r = 0; r < 4; r++) {
#pragma unroll
    for (int m = 1; m < 16; m <<= 1) ss[r] += __shfl_xor(ss[r], m);
  }
  float inv[4];
#pragma unroll
  for (int r = 0; r < 4; r++) inv[r] = 1.0f / fmaxf(sqrtf(ss[r]), 1e-12f);

#pragma unroll
  for (int nt = 0; nt < 8; nt++) {
#pragma unroll
    for (int r = 0; r < 4; r++) {
      o[(size_t)(row0 + lh * 4 + r) * DD + nt * 16 + lm] = h[nt][r] * inv[r];
    }
  }
}

// ---------------------------------------------------------------------------
extern "C" void kernel_launch(void* const* d_in, const int* in_sizes, int n_in,
                              void* d_out, int out_size, void* d_ws, size_t ws_size,
                              hipStream_t stream) {
  const float* fu  = (const float*)d_in[0];
  const float* fi  = (const float*)d_in[1];
  const float* nu  = (const float*)d_in[2];
  const float* ni  = (const float*)d_in[3];
  const float* nui = (const float*)d_in[4];
  const float* niu = (const float*)d_in[5];
  const float* W1  = (const float*)d_in[6];
  const float* b1  = (const float*)d_in[7];
  const float* W2  = (const float*)d_in[8];
  const float* b2  = (const float*)d_in[9];
  const int* eu    = (const int*)d_in[10];
  const int* ei    = (const int*)d_in[11];
  float* out = (float*)d_out;
  char* ws = (char*)d_ws;

  size_t off_b = 0;
  auto alloc = [&](size_t bytes) {
    char* p = ws + off_b;
    off_b += (bytes + 255) & ~(size_t)255;
    return p;
  };
  unsigned short* Xub = (unsigned short*)alloc((size_t)NU_ * DD * 2);
  unsigned short* Mub = (unsigned short*)alloc((size_t)NU_ * DD * 2);
  unsigned short* Xib = (unsigned short*)alloc((size_t)NI_ * DD * 2);
  unsigned short* Mib = (unsigned short*)alloc((size_t)NI_ * DD * 2);
  unsigned short* fub = (unsigned short*)alloc((size_t)NU_ * DD * 2);
  unsigned short* fib = (unsigned short*)alloc((size_t)NI_ * DD * 2);
  unsigned short* Bp  = (unsigned short*)alloc(4096 * 8 * 2);
  int* hist = (int*)alloc((size_t)NL * 4);
  int* offc = (int*)alloc((size_t)NL * 4);
  int* bsum = (int*)alloc(128 * 4);
  int2* binned = (int2*)alloc((size_t)2 * E_ * 8);

  pack_kernel<<<16, 256, 0, stream>>>(W1, W2, Bp);
  tobf_kernel<<<(NU_ * DD / 8 + 255) / 256, 256, 0, stream>>>(fu, fub, NU_ * DD / 8);
  tobf_kernel<<<(NI_ * DD / 8 + 255) / 256, 256, 0, stream>>>(fi, fib, NI_ * DD / 8);

  hist_kernel<<<NSB, 512, 0, stream>>>(eu, ei, hist);
  scanA_kernel<<<NSCB, 256, 0, stream>>>(hist, offc, bsum);
  scanB_kernel<<<1, 64, 0, stream>>>(bsum);
  scanC_kernel<<<(NL + 255) / 256, 256, 0, stream>>>(offc, bsum);
  scatter_kernel<<<NSB, 512, 0, stream>>>(eu, ei, nui, niu, offc, binned);

  gatherb_kernel<<<NBKT, 512, 0, stream>>>(
      fu, fi, fub, fib, nu, ni, offc, binned, Xub, Mub, Xib, Mib);

  gemm_mfma_kernel<<<(NTILE_ALL + 7) / 8, 512, 0, stream>>>(
      Xub, Mub, Xib, Mib, Bp, b1, b2, out);
}

// Round 5
// 216.121 us; speedup vs baseline: 19.4828x; 1.0139x over previous
//
#include <hip/hip_runtime.h>

#define NU_ 100000
#define NI_ 50000
#define E_  600000
#define DD  128
#define NT_ (NU_ + NI_)
#define NTILE_U (NU_ / 16)    // 6250
#define NTILE_ALL (NT_ / 16)  // 9375

// bucketed CSR build
#define NBKT ((NT_ + 127) >> 7)        // 1172 buckets of 128 nodes
#define SBLK 8192                       // edges per scatter block
#define NSB ((E_ + SBLK - 1) / SBLK)    // 74
#define NL (NBKT * NSB)                 // 86728 (bucket,block) cells
#define NSCB ((NL + 2047) / 2048)       // 43 scan blocks
#define MAXE 3072                       // max entries per bucket (mean 1024)

typedef short bf16x8 __attribute__((ext_vector_type(8)));
typedef float f32x4 __attribute__((ext_vector_type(4)));
typedef unsigned short u16x8 __attribute__((ext_vector_type(8)));

__device__ __forceinline__ unsigned short f2bf(float x) {
  unsigned u = __float_as_uint(x);
  return (unsigned short)((u + 0x7FFFu + ((u >> 16) & 1u)) >> 16);  // RNE
}
__device__ __forceinline__ float bf2f(unsigned short h) {
  return __uint_as_float((unsigned)h << 16);
}

// logical scan index L = bkt*NSB + sb  <->  storage idx = sb*NBKT + bkt
__device__ __forceinline__ int sidx(int L) {
  int bkt = L / NSB;
  int sb = L - bkt * NSB;
  return sb * NBKT + bkt;
}

// ---------------------------------------------------------------------------
// Pack W1,W2 into mfma_f32_16x16x32_bf16 B-fragment order.
// ---------------------------------------------------------------------------
__global__ __launch_bounds__(256) void pack_kernel(
    const float* __restrict__ W1, const float* __restrict__ W2,
    unsigned short* __restrict__ Bp) {
  int t = blockIdx.x * 256 + threadIdx.x;  // 4096 total
  if (t >= 4096) return;
  int w = t >> 11;
  int l = t & 63;
  int kt = (t >> 6) & 3;
  int nt = (t >> 8) & 7;
  const float* W = w ? W2 : W1;
  int n = nt * 16 + (l & 15);
  int k0 = kt * 32 + (l >> 4) * 8;
  unsigned short* dst = Bp + (size_t)t * 8;
#pragma unroll
  for (int j = 0; j < 8; j++) dst[j] = f2bf(W[n * DD + k0 + j]);
}

// ---------------------------------------------------------------------------
// f32 -> bf16 feature tables
// ---------------------------------------------------------------------------
__global__ __launch_bounds__(256) void tobf_kernel(
    const float* __restrict__ src, unsigned short* __restrict__ dst, int n8) {
  int t = blockIdx.x * 256 + threadIdx.x;
  if (t >= n8) return;
  const float4 v0 = reinterpret_cast<const float4*>(src)[t * 2];
  const float4 v1 = reinterpret_cast<const float4*>(src)[t * 2 + 1];
  u16x8 o;
  o[0] = f2bf(v0.x); o[1] = f2bf(v0.y); o[2] = f2bf(v0.z); o[3] = f2bf(v0.w);
  o[4] = f2bf(v1.x); o[5] = f2bf(v1.y); o[6] = f2bf(v1.z); o[7] = f2bf(v1.w);
  reinterpret_cast<u16x8*>(dst)[t] = o;
}

// ---------------------------------------------------------------------------
// Pass A: per-(scatter-block, bucket) histogram.
// ---------------------------------------------------------------------------
__global__ __launch_bounds__(512) void hist_kernel(
    const int* __restrict__ eu, const int* __restrict__ ei, int* __restrict__ hist) {
  __shared__ int cnt[NBKT];
  int sb = blockIdx.x, tid = threadIdx.x;
  for (int k = tid; k < NBKT; k += 512) cnt[k] = 0;
  __syncthreads();
#pragma unroll
  for (int j = 0; j < SBLK / 512; j++) {
    int e = sb * SBLK + j * 512 + tid;
    if (e < E_) {
      atomicAdd(&cnt[eu[e] >> 7], 1);
      atomicAdd(&cnt[(NU_ + ei[e]) >> 7], 1);
    }
  }
  __syncthreads();
  for (int k = tid; k < NBKT; k += 512) hist[sb * NBKT + k] = cnt[k];
}

// ---------------------------------------------------------------------------
// Scan over NL cells in logical (bucket-major) order.
// ---------------------------------------------------------------------------
__global__ __launch_bounds__(256) void scanA_kernel(
    const int* __restrict__ hist, int* __restrict__ off, int* __restrict__ bsum) {
  __shared__ int ts[256];
  int tid = threadIdx.x;
  int base = blockIdx.x * 2048 + tid * 8;
  int v[8];
  int s = 0;
#pragma unroll
  for (int j = 0; j < 8; j++) {
    v[j] = s;
    int L = base + j;
    s += (L < NL) ? hist[sidx(L)] : 0;
  }
  ts[tid] = s;
  __syncthreads();
  for (int ofs = 1; ofs < 256; ofs <<= 1) {
    int add = (tid >= ofs) ? ts[tid - ofs] : 0;
    __syncthreads();
    ts[tid] += add;
    __syncthreads();
  }
  int texcl = ts[tid] - s;
#pragma unroll
  for (int j = 0; j < 8; j++) {
    int L = base + j;
    if (L < NL) off[sidx(L)] = texcl + v[j];
  }
  if (tid == 255) bsum[blockIdx.x] = ts[255];
}

__global__ void scanB_kernel(int* __restrict__ bsum) {
  if (threadIdx.x == 0) {
    int s = 0;
    for (int n = 0; n < NSCB; n++) {
      int t = bsum[n];
      bsum[n] = s;
      s += t;
    }
  }
}

__global__ __launch_bounds__(256) void scanC_kernel(
    int* __restrict__ off, const int* __restrict__ bsum) {
  int L = blockIdx.x * 256 + threadIdx.x;
  if (L >= NL) return;
  off[sidx(L)] += bsum[L >> 11];
}

// ---------------------------------------------------------------------------
// Pass C: scatter edges into bucket-sorted array.
// entry.x = (g_local<<20) | neighbor_idx ; entry.y = weight bits
// ---------------------------------------------------------------------------
__global__ __launch_bounds__(512) void scatter_kernel(
    const int* __restrict__ eu, const int* __restrict__ ei,
    const float* __restrict__ nui, const float* __restrict__ niu,
    const int* __restrict__ off, int2* __restrict__ binned) {
  __shared__ int cur[NBKT];
  int sb = blockIdx.x, tid = threadIdx.x;
  for (int k = tid; k < NBKT; k += 512) cur[k] = off[sb * NBKT + k];
  __syncthreads();
#pragma unroll
  for (int j = 0; j < SBLK / 512; j++) {
    int e = sb * SBLK + j * 512 + tid;
    if (e < E_) {
      int u = eu[e], i = ei[e];
      int gi = NU_ + i;
      int s1 = atomicAdd(&cur[u >> 7], 1);
      binned[s1] = make_int2(((u & 127) << 20) | i, __float_as_int(niu[e]));
      int s2 = atomicAdd(&cur[gi >> 7], 1);
      binned[s2] = make_int2(((gi & 127) << 20) | u, __float_as_int(nui[e]));
    }
  }
}

// ---------------------------------------------------------------------------
// Pass D: per-bucket gather. Build 128-node CSR in LDS, then 8 waves x 16
// nodes; 4 neighbors per step (quarter-wave each, ushort8/lane),
// shfl_xor(16)+shfl_xor(32) combine. Own features read from bf16 tables.
//   X[g] = feat[g] + sum fnb[idx]*w
//   M[g] = feat[g]*s_own .* sum fnb[idx]*s_nb[idx]
// ---------------------------------------------------------------------------
__global__ __launch_bounds__(512) void gatherb_kernel(
    const unsigned short* __restrict__ fub, const unsigned short* __restrict__ fib,
    const float* __restrict__ nu, const float* __restrict__ ni,
    const int* __restrict__ off, const int2* __restrict__ binned,
    unsigned short* __restrict__ Xu, unsigned short* __restrict__ Mu,
    unsigned short* __restrict__ Xi, unsigned short* __restrict__ Mi) {
  __shared__ int2 ent[MAXE];
  __shared__ int ncnt[128];
  __shared__ int nstart[129];
  __shared__ int ncur[128];

  int bkt = blockIdx.x, tid = threadIdx.x;
  int bs = off[bkt];  // storage idx (sb=0, bkt) == bucket start
  int be = (bkt + 1 < NBKT) ? off[bkt + 1] : 2 * E_;
  int cnt = be - bs;
  if (cnt > MAXE) cnt = MAXE;

  if (tid < 128) ncnt[tid] = 0;
  __syncthreads();
  for (int k = tid; k < cnt; k += 512)
    atomicAdd(&ncnt[(binned[bs + k].x >> 20) & 127], 1);
  __syncthreads();

  if (tid == 0) nstart[0] = 0;
  if (tid < 128) nstart[tid + 1] = ncnt[tid];
  __syncthreads();
  for (int ofs = 1; ofs < 128; ofs <<= 1) {
    int v = 0;
    if (tid < 128 && tid >= ofs) v = nstart[tid + 1 - ofs];
    __syncthreads();
    if (tid < 128) nstart[tid + 1] += v;
    __syncthreads();
  }
  if (tid < 128) ncur[tid] = nstart[tid];
  __syncthreads();

  for (int k = tid; k < cnt; k += 512) {
    int2 a = binned[bs + k];
    int slot = atomicAdd(&ncur[(a.x >> 20) & 127], 1);
    ent[slot] = a;
  }
  __syncthreads();

  int wid = tid >> 6, lane = tid & 63;
  int q = lane >> 4, sub = lane & 15;

  for (int nn = 0; nn < 16; nn++) {
    int gl = wid * 16 + nn;
    int g = bkt * 128 + gl;
    if (g >= NT_) break;
    bool isU = g < NU_;
    const unsigned short* nbF = isU ? fib : fub;
    const float* nbS = isU ? ni : nu;
    int cs = nstart[gl], ce = nstart[gl + 1];

    float aA[8] = {0.f, 0.f, 0.f, 0.f, 0.f, 0.f, 0.f, 0.f};
    float aM[8] = {0.f, 0.f, 0.f, 0.f, 0.f, 0.f, 0.f, 0.f};
    for (int j = cs + q; j < ce; j += 4) {
      int2 a = ent[j];
      int idx = a.x & 0xFFFFF;
      float w = __int_as_float(a.y);
      float snb = nbS[idx];
      u16x8 f = *reinterpret_cast<const u16x8*>(nbF + (size_t)idx * DD + sub * 8);
#pragma unroll
      for (int d = 0; d < 8; d++) {
        float r = bf2f((unsigned short)f[d]);
        aA[d] += r * w;
        aM[d] += r * snb;
      }
    }
#pragma unroll
    for (int d = 0; d < 8; d++) {
      aA[d] += __shfl_xor(aA[d], 16);
      aA[d] += __shfl_xor(aA[d], 32);
      aM[d] += __shfl_xor(aM[d], 16);
      aM[d] += __shfl_xor(aM[d], 32);
    }

    int lrow = isU ? g : g - NU_;
    if (q < 2) {
      const unsigned short* ownp = (isU ? fub : fib) + (size_t)lrow * DD + sub * 8;
      u16x8 fo = *reinterpret_cast<const u16x8*>(ownp);
      u16x8 o;
      if (q == 0) {
#pragma unroll
        for (int d = 0; d < 8; d++)
          o[d] = f2bf(bf2f((unsigned short)fo[d]) + aA[d]);
        *reinterpret_cast<u16x8*>((isU ? Xu : Xi) + (size_t)lrow * DD + sub * 8) = o;
      } else {
        float so = isU ? nu[lrow] : ni[lrow];
#pragma unroll
        for (int d = 0; d < 8; d++)
          o[d] = f2bf(bf2f((unsigned short)fo[d]) * so * aM[d]);
        *reinterpret_cast<u16x8*>((isU ? Mu : Mi) + (size_t)lrow * DD + sub * 8) = o;
      }
    }
  }
}

// ---------------------------------------------------------------------------
// MFMA GEMM + fused epilogue.
// ---------------------------------------------------------------------------
__global__ __launch_bounds__(512) void gemm_mfma_kernel(
    const unsigned short* __restrict__ Xu, const unsigned short* __restrict__ Mu,
    const unsigned short* __restrict__ Xi, const unsigned short* __restrict__ Mi,
    const unsigned short* __restrict__ Bp,
    const float* __restrict__ b1, const float* __restrict__ b2,
    float* __restrict__ out) {
  __shared__ __align__(16) unsigned short Bs[32768];  // 64 KB

  {
    const float4* src = reinterpret_cast<const float4*>(Bp);
    float4* dst = reinterpret_cast<float4*>(Bs);
    for (int i = threadIdx.x; i < 4096; i += 512) dst[i] = src[i];
  }
  __syncthreads();

  int wid = threadIdx.x >> 6;
  int lane = threadIdx.x & 63;
  int gt = blockIdx.x * 8 + wid;
  if (gt >= NTILE_ALL) return;

  const unsigned short* X;
  const unsigned short* M;
  float* o;
  int row0;
  if (gt < NTILE_U) {
    X = Xu; M = Mu; o = out; row0 = gt * 16;
  } else {
    X = Xi; M = Mi; o = out + (size_t)NU_ * DD; row0 = (gt - NTILE_U) * 16;
  }

  int lm = lane & 15, lh = lane >> 4;
  const unsigned short* xb = X + (size_t)(row0 + lm) * DD + lh * 8;
  const unsigned short* mb = M + (size_t)(row0 + lm) * DD + lh * 8;

  bf16x8 a1[4], a2[4];
#pragma unroll
  for (int kt = 0; kt < 4; kt++) {
    a1[kt] = *reinterpret_cast<const bf16x8*>(xb + kt * 32);
    a2[kt] = *reinterpret_cast<const bf16x8*>(mb + kt * 32);
  }

  f32x4 acc[8];
#pragma unroll
  for (int nt = 0; nt < 8; nt++) {
    f32x4 c = {0.f, 0.f, 0.f, 0.f};
#pragma unroll
    for (int kt = 0; kt < 4; kt++) {
      bf16x8 bf1 = *reinterpret_cast<const bf16x8*>(Bs + ((size_t)((0 * 8 + nt) * 4 + kt) * 64 + lane) * 8);
      c = __builtin_amdgcn_mfma_f32_16x16x32_bf16(a1[kt], bf1, c, 0, 0, 0);
      bf16x8 bf2 = *reinterpret_cast<const bf16x8*>(Bs + ((size_t)((1 * 8 + nt) * 4 + kt) * 64 + lane) * 8);
      c = __builtin_amdgcn_mfma_f32_16x16x32_bf16(a2[kt], bf2, c, 0, 0, 0);
    }
    acc[nt] = c;
  }

  float h[8][4];
  float ss[4] = {0.f, 0.f, 0.f, 0.f};
#pragma unroll
  for (int nt = 0; nt < 8; nt++) {
    float bb = b1[nt * 16 + lm] + b2[nt * 16 + lm];
#pragma unroll
    for (int r = 0; r < 4; r++) {
      float v = acc[nt][r] + bb;
      v = (v > 0.f) ? v : 0.2f * v;
      h[nt][r] = v;
      ss[r] += v * v;
    }
  }
#pragma unroll
  for (int r = 0; r < 4; r++) {
#pragma unroll
    for (int m = 1; m < 16; m <<= 1) ss[r] += __shfl_xor(ss[r], m);
  }
  float inv[4];
#pragma unroll
  for (int r = 0; r < 4; r++) inv[r] = 1.0f / fmaxf(sqrtf(ss[r]), 1e-12f);

#pragma unroll
  for (int nt = 0; nt < 8; nt++) {
#pragma unroll
    for (int r = 0; r < 4; r++) {
      o[(size_t)(row0 + lh * 4 + r) * DD + nt * 16 + lm] = h[nt][r] * inv[r];
    }
  }
}

// ---------------------------------------------------------------------------
extern "C" void kernel_launch(void* const* d_in, const int* in_sizes, int n_in,
                              void* d_out, int out_size, void* d_ws, size_t ws_size,
                              hipStream_t stream) {
  const float* fu  = (const float*)d_in[0];
  const float* fi  = (const float*)d_in[1];
  const float* nu  = (const float*)d_in[2];
  const float* ni  = (const float*)d_in[3];
  const float* nui = (const float*)d_in[4];
  const float* niu = (const float*)d_in[5];
  const float* W1  = (const float*)d_in[6];
  const float* b1  = (const float*)d_in[7];
  const float* W2  = (const float*)d_in[8];
  const float* b2  = (const float*)d_in[9];
  const int* eu    = (const int*)d_in[10];
  const int* ei    = (const int*)d_in[11];
  float* out = (float*)d_out;
  char* ws = (char*)d_ws;

  size_t off_b = 0;
  auto alloc = [&](size_t bytes) {
    char* p = ws + off_b;
    off_b += (bytes + 255) & ~(size_t)255;
    return p;
  };
  unsigned short* Xub = (unsigned short*)alloc((size_t)NU_ * DD * 2);
  unsigned short* Mub = (unsigned short*)alloc((size_t)NU_ * DD * 2);
  unsigned short* Xib = (unsigned short*)alloc((size_t)NI_ * DD * 2);
  unsigned short* Mib = (unsigned short*)alloc((size_t)NI_ * DD * 2);
  unsigned short* fub = (unsigned short*)alloc((size_t)NU_ * DD * 2);
  unsigned short* fib = (unsigned short*)alloc((size_t)NI_ * DD * 2);
  unsigned short* Bp  = (unsigned short*)alloc(4096 * 8 * 2);
  int* hist = (int*)alloc((size_t)NL * 4);
  int* offc = (int*)alloc((size_t)NL * 4);
  int* bsum = (int*)alloc(128 * 4);
  int2* binned = (int2*)alloc((size_t)2 * E_ * 8);

  pack_kernel<<<16, 256, 0, stream>>>(W1, W2, Bp);
  tobf_kernel<<<(NU_ * DD / 8 + 255) / 256, 256, 0, stream>>>(fu, fub, NU_ * DD / 8);
  tobf_kernel<<<(NI_ * DD / 8 + 255) / 256, 256, 0, stream>>>(fi, fib, NI_ * DD / 8);

  hist_kernel<<<NSB, 512, 0, stream>>>(eu, ei, hist);
  scanA_kernel<<<NSCB, 256, 0, stream>>>(hist, offc, bsum);
  scanB_kernel<<<1, 64, 0, stream>>>(bsum);
  scanC_kernel<<<(NL + 255) / 256, 256, 0, stream>>>(offc, bsum);
  scatter_kernel<<<NSB, 512, 0, stream>>>(eu, ei, nui, niu, offc, binned);

  gatherb_kernel<<<NBKT, 512, 0, stream>>>(
      fub, fib, nu, ni, offc, binned, Xub, Mub, Xib, Mib);

  gemm_mfma_kernel<<<(NTILE_ALL + 7) / 8, 512, 0, stream>>>(
      Xub, Mub, Xib, Mib, Bp, b1, b2, out);
}

// Round 7
// 208.228 us; speedup vs baseline: 20.2213x; 1.0379x over previous
//
#include <hip/hip_runtime.h>
#include <hip/hip_fp16.h>

#define NU_ 100000
#define NI_ 50000
#define E_  600000
#define DD  128
#define NT_ (NU_ + NI_)

// bucketed CSR build
#define NBKT ((NT_ + 127) >> 7)        // 1172 buckets of 128 nodes
#define SBLK 8192                       // edges per scatter block
#define NSB ((E_ + SBLK - 1) / SBLK)    // 74
#define NL (NBKT * NSB)                 // 86728 (bucket,block) cells
#define NSCB ((NL + 2047) / 2048)       // 43 scan blocks
// per-bucket entries: USER buckets mean 128*6=768; ITEM buckets mean 128*12=1536,
// sd ~39 -> 2048 is 13 sigma above the item mean. (1536 was the bug: == mean.)
#define MAXE 2048

typedef short bf16x8 __attribute__((ext_vector_type(8)));
typedef float f32x4 __attribute__((ext_vector_type(4)));
typedef unsigned short u16x8 __attribute__((ext_vector_type(8)));

__device__ __forceinline__ unsigned short f2bf(float x) {
  unsigned u = __float_as_uint(x);
  return (unsigned short)((u + 0x7FFFu + ((u >> 16) & 1u)) >> 16);  // RNE
}
__device__ __forceinline__ float bf2f(unsigned short h) {
  return __uint_as_float((unsigned)h << 16);
}

// logical scan index L = bkt*NSB + sb  <->  storage idx = sb*NBKT + bkt
__device__ __forceinline__ int sidx(int L) {
  int bkt = L / NSB;
  int sb = L - bkt * NSB;
  return sb * NBKT + bkt;
}

// LDS A-tile swizzle: row nn (256 B rows), byte-in-row b (16B aligned),
// XOR byte bits 4-6 with row bits 0-2
__device__ __forceinline__ int swz(int nn, int b) {
  return nn * 256 + (b ^ ((nn & 7) << 4));
}

// ---------------------------------------------------------------------------
// Pack W1,W2 into mfma_f32_16x16x32_bf16 B-fragment order.
// Bp[w][nt][kt][lane][j] = W[nt*16 + (lane&15)][kt*32 + (lane>>4)*8 + j]
// ---------------------------------------------------------------------------
__global__ __launch_bounds__(256) void pack_kernel(
    const float* __restrict__ W1, const float* __restrict__ W2,
    unsigned short* __restrict__ Bp) {
  int t = blockIdx.x * 256 + threadIdx.x;  // 4096 total
  if (t >= 4096) return;
  int w = t >> 11;
  int l = t & 63;
  int kt = (t >> 6) & 3;
  int nt = (t >> 8) & 7;
  const float* W = w ? W2 : W1;
  int n = nt * 16 + (l & 15);
  int k0 = kt * 32 + (l >> 4) * 8;
  unsigned short* dst = Bp + (size_t)t * 8;
#pragma unroll
  for (int j = 0; j < 8; j++) dst[j] = f2bf(W[n * DD + k0 + j]);
}

// ---------------------------------------------------------------------------
// f32 -> bf16 both feature tables, one launch
// ---------------------------------------------------------------------------
__global__ __launch_bounds__(256) void tobf_kernel(
    const float* __restrict__ fu, const float* __restrict__ fi,
    unsigned short* __restrict__ fub, unsigned short* __restrict__ fib) {
  int t = blockIdx.x * 256 + threadIdx.x;
  int nu8 = NU_ * DD / 8;
  int nt8 = NT_ * DD / 8;
  if (t >= nt8) return;
  const float* src;
  unsigned short* dst;
  int k;
  if (t < nu8) { src = fu; dst = fub; k = t; }
  else { src = fi; dst = fib; k = t - nu8; }
  const float4 v0 = reinterpret_cast<const float4*>(src)[k * 2];
  const float4 v1 = reinterpret_cast<const float4*>(src)[k * 2 + 1];
  u16x8 o;
  o[0] = f2bf(v0.x); o[1] = f2bf(v0.y); o[2] = f2bf(v0.z); o[3] = f2bf(v0.w);
  o[4] = f2bf(v1.x); o[5] = f2bf(v1.y); o[6] = f2bf(v1.z); o[7] = f2bf(v1.w);
  reinterpret_cast<u16x8*>(dst)[k] = o;
}

// ---------------------------------------------------------------------------
// Pass A: per-(scatter-block, bucket) histogram.
// ---------------------------------------------------------------------------
__global__ __launch_bounds__(512) void hist_kernel(
    const int* __restrict__ eu, const int* __restrict__ ei, int* __restrict__ hist) {
  __shared__ int cnt[NBKT];
  int sb = blockIdx.x, tid = threadIdx.x;
  for (int k = tid; k < NBKT; k += 512) cnt[k] = 0;
  __syncthreads();
#pragma unroll
  for (int j = 0; j < SBLK / 512; j++) {
    int e = sb * SBLK + j * 512 + tid;
    if (e < E_) {
      atomicAdd(&cnt[eu[e] >> 7], 1);
      atomicAdd(&cnt[(NU_ + ei[e]) >> 7], 1);
    }
  }
  __syncthreads();
  for (int k = tid; k < NBKT; k += 512) hist[sb * NBKT + k] = cnt[k];
}

// ---------------------------------------------------------------------------
// Scan over NL cells in logical (bucket-major) order.
// ---------------------------------------------------------------------------
__global__ __launch_bounds__(256) void scanA_kernel(
    const int* __restrict__ hist, int* __restrict__ off, int* __restrict__ bsum) {
  __shared__ int ts[256];
  int tid = threadIdx.x;
  int base = blockIdx.x * 2048 + tid * 8;
  int v[8];
  int s = 0;
#pragma unroll
  for (int j = 0; j < 8; j++) {
    v[j] = s;
    int L = base + j;
    s += (L < NL) ? hist[sidx(L)] : 0;
  }
  ts[tid] = s;
  __syncthreads();
  for (int ofs = 1; ofs < 256; ofs <<= 1) {
    int add = (tid >= ofs) ? ts[tid - ofs] : 0;
    __syncthreads();
    ts[tid] += add;
    __syncthreads();
  }
  int texcl = ts[tid] - s;
#pragma unroll
  for (int j = 0; j < 8; j++) {
    int L = base + j;
    if (L < NL) off[sidx(L)] = texcl + v[j];
  }
  if (tid == 255) bsum[blockIdx.x] = ts[255];
}

__global__ void scanB_kernel(int* __restrict__ bsum) {
  if (threadIdx.x == 0) {
    int s = 0;
    for (int n = 0; n < NSCB; n++) {
      int t = bsum[n];
      bsum[n] = s;
      s += t;
    }
  }
}

__global__ __launch_bounds__(256) void scanC_kernel(
    int* __restrict__ off, const int* __restrict__ bsum) {
  int L = blockIdx.x * 256 + threadIdx.x;
  if (L >= NL) return;
  off[sidx(L)] += bsum[L >> 11];
}

// ---------------------------------------------------------------------------
// Pass C: scatter edges into bucket-sorted array.
// entry.x = (g_local<<20) | neighbor_idx ; entry.y = weight bits
// ---------------------------------------------------------------------------
__global__ __launch_bounds__(512) void scatter_kernel(
    const int* __restrict__ eu, const int* __restrict__ ei,
    const float* __restrict__ nui, const float* __restrict__ niu,
    const int* __restrict__ off, int2* __restrict__ binned) {
  __shared__ int cur[NBKT];
  int sb = blockIdx.x, tid = threadIdx.x;
  for (int k = tid; k < NBKT; k += 512) cur[k] = off[sb * NBKT + k];
  __syncthreads();
#pragma unroll
  for (int j = 0; j < SBLK / 512; j++) {
    int e = sb * SBLK + j * 512 + tid;
    if (e < E_) {
      int u = eu[e], i = ei[e];
      int gi = NU_ + i;
      int s1 = atomicAdd(&cur[u >> 7], 1);
      binned[s1] = make_int2(((u & 127) << 20) | i, __float_as_int(niu[e]));
      int s2 = atomicAdd(&cur[gi >> 7], 1);
      binned[s2] = make_int2(((gi & 127) << 20) | u, __float_as_int(nui[e]));
    }
  }
}

// ---------------------------------------------------------------------------
// Fused gather + MFMA GEMM + epilogue. One block = one 128-node bucket =
// 8 MFMA row-tiles. Gather writes bf16 X/M into swizzled LDS; barrier;
// each wave runs the 16x128 double-GEMM for its tile and stores normalized
// output. Entry staging split into eidx (int) + ew (fp16) to fit 2 blocks/CU.
// ---------------------------------------------------------------------------
__global__ __launch_bounds__(512) void fused_kernel(
    const unsigned short* __restrict__ fub, const unsigned short* __restrict__ fib,
    const float* __restrict__ nu, const float* __restrict__ ni,
    const int* __restrict__ off, const int2* __restrict__ binned,
    const unsigned short* __restrict__ Bp,
    const float* __restrict__ b1, const float* __restrict__ b2,
    float* __restrict__ out) {
  __shared__ __align__(16) unsigned short Xs[128 * 128];  // 32 KB, swizzled rows
  __shared__ __align__(16) unsigned short Ms[128 * 128];  // 32 KB
  __shared__ int eidx[MAXE];                              // 8 KB
  __shared__ unsigned short ew[MAXE];                     // 4 KB (fp16 weights)
  __shared__ int ncnt[128];
  __shared__ int nstart[129];
  __shared__ int ncur[128];

  int bkt = blockIdx.x, tid = threadIdx.x;
  int bs = off[bkt];  // storage idx (sb=0, bkt) == bucket start
  int be = (bkt + 1 < NBKT) ? off[bkt + 1] : 2 * E_;
  int cnt = be - bs;
  if (cnt > MAXE) cnt = MAXE;  // 13-sigma safety net

  // ---- per-node CSR in LDS ----
  if (tid < 128) ncnt[tid] = 0;
  __syncthreads();
  for (int k = tid; k < cnt; k += 512)
    atomicAdd(&ncnt[(binned[bs + k].x >> 20) & 127], 1);
  __syncthreads();

  if (tid == 0) nstart[0] = 0;
  if (tid < 128) nstart[tid + 1] = ncnt[tid];
  __syncthreads();
  for (int ofs = 1; ofs < 128; ofs <<= 1) {
    int v = 0;
    if (tid < 128 && tid >= ofs) v = nstart[tid + 1 - ofs];
    __syncthreads();
    if (tid < 128) nstart[tid + 1] += v;
    __syncthreads();
  }
  if (tid < 128) ncur[tid] = nstart[tid];
  __syncthreads();

  for (int k = tid; k < cnt; k += 512) {
    int2 a = binned[bs + k];
    int slot = atomicAdd(&ncur[(a.x >> 20) & 127], 1);
    eidx[slot] = a.x;
    ew[slot] = __half_as_ushort(__float2half(__int_as_float(a.y)));
  }
  __syncthreads();

  int wid = tid >> 6, lane = tid & 63;
  int q = lane >> 4, sub = lane & 15;

  // ---- gather phase: 16 nodes per wave, quarter-wave per neighbor ----
  for (int nn = 0; nn < 16; nn++) {
    int gl = wid * 16 + nn;
    int g = bkt * 128 + gl;
    if (g >= NT_) break;
    bool isU = g < NU_;
    const unsigned short* nbF = isU ? fib : fub;
    const float* nbS = isU ? ni : nu;
    int cs = nstart[gl], ce = nstart[gl + 1];

    float aA[8] = {0.f, 0.f, 0.f, 0.f, 0.f, 0.f, 0.f, 0.f};
    float aM[8] = {0.f, 0.f, 0.f, 0.f, 0.f, 0.f, 0.f, 0.f};
    for (int j = cs + q; j < ce; j += 4) {
      int idx = eidx[j] & 0xFFFFF;
      float w = __half2float(__ushort_as_half(ew[j]));
      float snb = nbS[idx];
      u16x8 f = *reinterpret_cast<const u16x8*>(nbF + (size_t)idx * DD + sub * 8);
#pragma unroll
      for (int d = 0; d < 8; d++) {
        float r = bf2f((unsigned short)f[d]);
        aA[d] += r * w;
        aM[d] += r * snb;
      }
    }
#pragma unroll
    for (int d = 0; d < 8; d++) {
      aA[d] += __shfl_xor(aA[d], 16);
      aA[d] += __shfl_xor(aA[d], 32);
      aM[d] += __shfl_xor(aM[d], 16);
      aM[d] += __shfl_xor(aM[d], 32);
    }

    int lrow = isU ? g : g - NU_;
    if (q < 2) {
      const unsigned short* ownp = (isU ? fub : fib) + (size_t)lrow * DD + sub * 8;
      u16x8 fo = *reinterpret_cast<const u16x8*>(ownp);
      u16x8 o;
      if (q == 0) {
#pragma unroll
        for (int d = 0; d < 8; d++)
          o[d] = f2bf(bf2f((unsigned short)fo[d]) + aA[d]);
        *reinterpret_cast<u16x8*>((char*)Xs + swz(gl, sub * 16)) = o;
      } else {
        float so = isU ? nu[lrow] : ni[lrow];
#pragma unroll
        for (int d = 0; d < 8; d++)
          o[d] = f2bf(bf2f((unsigned short)fo[d]) * so * aM[d]);
        *reinterpret_cast<u16x8*>((char*)Ms + swz(gl, sub * 16)) = o;
      }
    }
  }
  __syncthreads();

  // ---- MFMA phase: wave wid does tile rows [bkt*128+wid*16, +16) ----
  int gt0 = bkt * 128 + wid * 16;
  if (gt0 >= NT_) return;  // tail bucket: user/item boundary is 16-aligned

  int lm = lane & 15, lh = lane >> 4;

  bf16x8 a1[4], a2[4];
#pragma unroll
  for (int kt = 0; kt < 4; kt++) {
    int b = kt * 64 + lh * 16;  // byte offset in row for dims kt*32 + lh*8 ..+7
    a1[kt] = *reinterpret_cast<const bf16x8*>((char*)Xs + swz(wid * 16 + lm, b));
    a2[kt] = *reinterpret_cast<const bf16x8*>((char*)Ms + swz(wid * 16 + lm, b));
  }

  f32x4 acc[8];
#pragma unroll
  for (int nt = 0; nt < 8; nt++) {
    f32x4 c = {0.f, 0.f, 0.f, 0.f};
#pragma unroll
    for (int kt = 0; kt < 4; kt++) {
      bf16x8 bf1 = *reinterpret_cast<const bf16x8*>(Bp + ((size_t)((0 * 8 + nt) * 4 + kt) * 64 + lane) * 8);
      c = __builtin_amdgcn_mfma_f32_16x16x32_bf16(a1[kt], bf1, c, 0, 0, 0);
      bf16x8 bf2 = *reinterpret_cast<const bf16x8*>(Bp + ((size_t)((1 * 8 + nt) * 4 + kt) * 64 + lane) * 8);
      c = __builtin_amdgcn_mfma_f32_16x16x32_bf16(a2[kt], bf2, c, 0, 0, 0);
    }
    acc[nt] = c;
  }

  // epilogue: bias -> leaky relu -> row L2 norm -> store.
  // C layout: local row = lh*4 + r, col = nt*16 + lm. out is flat by g.
  float h[8][4];
  float ss[4] = {0.f, 0.f, 0.f, 0.f};
#pragma unroll
  for (int nt = 0; nt < 8; nt++) {
    float bb = b1[nt * 16 + lm] + b2[nt * 16 + lm];
#pragma unroll
    for (int r = 0; r < 4; r++) {
      float v = acc[nt][r] + bb;
      v = (v > 0.f) ? v : 0.2f * v;
      h[nt][r] = v;
      ss[r] += v * v;
    }
  }
#pragma unroll
  for (int r = 0; r < 4; r++) {
#pragma unroll
    for (int m = 1; m < 16; m <<= 1) ss[r] += __shfl_xor(ss[r], m);
  }
  float inv[4];
#pragma unroll
  for (int r = 0; r < 4; r++) inv[r] = 1.0f / fmaxf(sqrtf(ss[r]), 1e-12f);

#pragma unroll
  for (int nt = 0; nt < 8; nt++) {
#pragma unroll
    for (int r = 0; r < 4; r++) {
      out[(size_t)(gt0 + lh * 4 + r) * DD + nt * 16 + lm] = h[nt][r] * inv[r];
    }
  }
}

// ---------------------------------------------------------------------------
extern "C" void kernel_launch(void* const* d_in, const int* in_sizes, int n_in,
                              void* d_out, int out_size, void* d_ws, size_t ws_size,
                              hipStream_t stream) {
  const float* fu  = (const float*)d_in[0];
  const float* fi  = (const float*)d_in[1];
  const float* nu  = (const float*)d_in[2];
  const float* ni  = (const float*)d_in[3];
  const float* nui = (const float*)d_in[4];
  const float* niu = (const float*)d_in[5];
  const float* W1  = (const float*)d_in[6];
  const float* b1  = (const float*)d_in[7];
  const float* W2  = (const float*)d_in[8];
  const float* b2  = (const float*)d_in[9];
  const int* eu    = (const int*)d_in[10];
  const int* ei    = (const int*)d_in[11];
  float* out = (float*)d_out;
  char* ws = (char*)d_ws;

  size_t off_b = 0;
  auto alloc = [&](size_t bytes) {
    char* p = ws + off_b;
    off_b += (bytes + 255) & ~(size_t)255;
    return p;
  };
  unsigned short* fub = (unsigned short*)alloc((size_t)NU_ * DD * 2);
  unsigned short* fib = (unsigned short*)alloc((size_t)NI_ * DD * 2);
  unsigned short* Bp  = (unsigned short*)alloc(4096 * 8 * 2);
  int* hist = (int*)alloc((size_t)NL * 4);
  int* offc = (int*)alloc((size_t)NL * 4);
  int* bsum = (int*)alloc(128 * 4);
  int2* binned = (int2*)alloc((size_t)2 * E_ * 8);

  pack_kernel<<<16, 256, 0, stream>>>(W1, W2, Bp);
  tobf_kernel<<<(NT_ * DD / 8 + 255) / 256, 256, 0, stream>>>(fu, fi, fub, fib);

  hist_kernel<<<NSB, 512, 0, stream>>>(eu, ei, hist);
  scanA_kernel<<<NSCB, 256, 0, stream>>>(hist, offc, bsum);
  scanB_kernel<<<1, 64, 0, stream>>>(bsum);
  scanC_kernel<<<(NL + 255) / 256, 256, 0, stream>>>(offc, bsum);
  scatter_kernel<<<NSB, 512, 0, stream>>>(eu, ei, nui, niu, offc, binned);

  fused_kernel<<<NBKT, 512, 0, stream>>>(
      fub, fib, nu, ni, offc, binned, Bp, b1, b2, out);
}